// Round 7
// baseline (708.641 us; speedup 1.0000x reference)
//
#include <hip/hip_runtime.h>
#include <cstdint>
#include <cstddef>

// B=8, C=64, T=250, F=161, H=64, Hh=32, BB=128
#define BBN 128
#define NBT 2000
#define NF  161
#define GROUP (NF * 64)       // 10304

typedef __attribute__((ext_vector_type(4))) float f32x4;
typedef __attribute__((ext_vector_type(8))) __bf16 bf16x8;
typedef __attribute__((ext_vector_type(8))) uint16_t u16x8;

__device__ __forceinline__ uint16_t bf16_rne_u16(float f) {
  uint32_t u = __float_as_uint(f);
  return (uint16_t)((u + 0x7fffu + ((u >> 16) & 1u)) >> 16);
}
__device__ __forceinline__ float bf16u_to_f(uint16_t h) {
  return __uint_as_float((uint32_t)h << 16);
}
// packed f32->bf16 RNE (1 op per pair; no builtin on gfx950 -> asm)
__device__ __forceinline__ uint32_t cvt_pk_bf16(float lo, float hi) {
  uint32_t r;
  asm("v_cvt_pk_bf16_f32 %0, %1, %2" : "=v"(r) : "v"(lo), "v"(hi));
  return r;
}
__device__ __forceinline__ float asm_exp2(float x) {  // 2^x
  float r;
  asm("v_exp_f32 %0, %1" : "=v"(r) : "v"(x));
  return r;
}
__device__ __forceinline__ float asm_rcp(float x) {
  float r;
  asm("v_rcp_f32 %0, %1" : "=v"(r) : "v"(x));
  return r;
}
// 1.7159*tanh(0.666x) = 1.7159 - 3.4318/(2^(1.9216698 x)+1)   (5 VALU)
__device__ __forceinline__ float lecun_tanh_f(float x) {
  float t = asm_exp2(1.9216698f * x);
  return fmaf(asm_rcp(t + 1.f), -3.4318f, 1.7159f);
}
__device__ __forceinline__ f32x4 mfma16(bf16x8 a, bf16x8 b, f32x4 c) {
  return __builtin_amdgcn_mfma_f32_16x16x32_bf16(a, b, c, 0, 0, 0);
}
__device__ __forceinline__ bf16x8 pack_frag(const float* __restrict__ base, int stride) {
  u16x8 t;
#pragma unroll
  for (int i = 0; i < 8; ++i) t[i] = bf16_rne_u16(base[i * stride]);
  return __builtin_bit_cast(bf16x8, t);
}

// Light block fence: drain own LDS ops (asm memory clobber orders all memory
// ops both directions), then raw barrier. No vmcnt drain (stores/prefetch
// stay in flight), no sched_barriers (scheduler free to overlap VALU/MFMA).
__device__ __forceinline__ void block_fence() {
  asm volatile("s_waitcnt lgkmcnt(0)" ::: "memory");
  __builtin_amdgcn_s_barrier();
}

// ---------- K0: x (B,C,T,F) -> xp_h (B*T,F,C) bf16 ----------
__global__ __launch_bounds__(256) void transpose_kernel(
    const float* __restrict__ x, uint16_t* __restrict__ xph) {
  __shared__ float tile[32][33];
  const int bt = blockIdx.x;
  const int b = bt / 250, t = bt - b * 250;
  const int f0 = blockIdx.y * 32;
  const int c0 = blockIdx.z * 32;
  const int tx = threadIdx.x & 31;
  const int ty4 = (threadIdx.x >> 5) * 4;
  const int f_in = f0 + tx;
#pragma unroll
  for (int i = 0; i < 4; ++i) {
    int c = c0 + ty4 + i;
    if (f_in < NF)
      tile[ty4 + i][tx] = x[((size_t)(b * 64 + c) * 250 + t) * NF + f_in];
  }
  __syncthreads();
  const int c_out = c0 + tx;
#pragma unroll
  for (int i = 0; i < 4; ++i) {
    int f = f0 + ty4 + i;
    if (f < NF) {
      size_t o = ((size_t)bt * NF + f) * 64 + c_out;
      xph[o] = bf16_rne_u16(tile[tx][ty4 + i]);
    }
  }
}

// ---------- K1/K3: 8-wave pipelined MFMA CfC scan ----------
// 16 sequences per 512-thread block. Wave w owns backbone n-tile w; waves
// 0..NM-1 own ff1 m-tile w. Weights in registers. Software pipeline: the
// x-part MFMAs for step t+1 run in phase B (accumulators a0/a1 carried in
// registers across the fence); phase A only adds the h-part + tanh.
// Activations cross phases through LDS in A-FRAGMENT ORDER (verified):
//   dest u16 index = ((c>>5)*64 + ((c&31)>>3)*16 + row)*8 + (c&7)
template <int HD>
__global__ __launch_bounds__(512) void mfma_scan8(
    const uint16_t* __restrict__ in, uint16_t* __restrict__ out,
    const float* __restrict__ Wb0, const float* __restrict__ bb0,
    const float* __restrict__ W10, const float* __restrict__ b10,
    const float* __restrict__ wt0, const float* __restrict__ A0,
    const float* __restrict__ Wb1, const float* __restrict__ bb1,
    const float* __restrict__ W11, const float* __restrict__ b11,
    const float* __restrict__ wt1, const float* __restrict__ A1,
    int seq_len, int blocksPerDir, int nseq, int seqs_per_outer,
    int outer_stride, int inner_stride, int step_stride,
    int o_seq_stride, int o_step_stride, int o_col_per_dir) {
  constexpr int NKH = HD / 32;   // h k-tiles (1 or 2)
  constexpr int NM = HD / 16;    // ff1 m-tiles (2 or 4)
  __shared__ __align__(16) uint16_t gfrag[4 * 64 * 8];    // g A-frags
  __shared__ __align__(16) uint16_t hfrag[NKH * 64 * 8];  // h A-frags

  const int dir = (blockIdx.x >= (unsigned)blocksPerDir) ? 1 : 0;
  const int bid = blockIdx.x - dir * blocksPerDir;
  const float* __restrict__ Wb = dir ? Wb1 : Wb0;
  const float* __restrict__ bb = dir ? bb1 : bb0;
  const float* __restrict__ W1 = dir ? W11 : W10;
  const float* __restrict__ b1 = dir ? b11 : b10;
  const float* __restrict__ wt = dir ? wt1 : wt0;
  const float* __restrict__ Aa = dir ? A1 : A0;
  const bool rev = (dir == 1);
  const int tid = threadIdx.x;
  const int w = tid >> 6, l = tid & 63, l4 = l >> 4, lm = l & 15;
  const bool has_m = (w < NM);

  // ---- weights in registers ----
  bf16x8 WB[2 + NKH];
#pragma unroll
  for (int kt = 0; kt < 2 + NKH; ++kt)
    WB[kt] = pack_frag(&Wb[(kt * 32 + l4 * 8) * BBN + 16 * w + lm], BBN);
  const float bbv = bb[16 * w + lm];
  const f32x4 bbv4 = {bbv, bbv, bbv, bbv};
  const f32x4 zero4 = {0.f, 0.f, 0.f, 0.f};
  bf16x8 W1f[4];
  f32x4 b1v4 = zero4;
  float mwt2 = 0.f, nAv = 0.f, Avv = 0.f;
  if (has_m) {
#pragma unroll
    for (int kt = 0; kt < 4; ++kt)
      W1f[kt] = pack_frag(&W1[(kt * 32 + l4 * 8) * HD + 16 * w + lm], HD);
    float b1v = b1[16 * w + lm];
    b1v4 = {b1v, b1v, b1v, b1v};
    mwt2 = -1.4426950408889634f * fabsf(wt[16 * w + lm]);
    Avv = Aa[16 * w + lm];
    nAv = -Avv;
  }

  // input base: A-frag row = sequence bid*16+lm (clamped for tail block)
  int sA = bid * 16 + lm;
  if (sA > nseq - 1) sA = nseq - 1;
  int ob = sA / seqs_per_outer, oi = sA - ob * seqs_per_outer;
  const uint16_t* inp =
      in + (size_t)ob * outer_stride + (size_t)oi * inner_stride + l4 * 8;
  // output bases (C-layout): seq = bid*16 + l4*4 + r, col = 16w+lm
  int obase[4];
  bool omask[4];
#pragma unroll
  for (int r = 0; r < 4; ++r) {
    int s = bid * 16 + l4 * 4 + r;
    omask[r] = has_m && (s < nseq);
    if (s > nseq - 1) s = nseq - 1;
    obase[r] = s * o_seq_stride + dir * o_col_per_dir + 16 * w + lm;
  }

  const int gi =
      ((w >> 1) * 64 + (2 * (w & 1) + (lm >> 3)) * 16 + l4 * 4) * 8 + (lm & 7);

  for (int e = tid; e < NKH * 64 * 8; e += 512) hfrag[e] = 0;  // h0 = 0
  block_fence();

  // preamble: load x(0), compute x-part accumulators for step 0
  bf16x8 nxa, nxb;
  {
    int f0 = rev ? (seq_len - 1) : 0;
    nxa = *(const bf16x8*)(inp + (size_t)f0 * step_stride);
    nxb = *(const bf16x8*)(inp + (size_t)f0 * step_stride + 32);
  }
  f32x4 a0 = mfma16(nxa, WB[0], bbv4);
  f32x4 a1 = mfma16(nxb, WB[1], zero4);

  for (int st = 0; st < seq_len; ++st) {
    // ---- phase A: prefetch x(st+1); h-part MFMA + tanh ----
    if (st + 1 < seq_len) {
      int f = rev ? (seq_len - 2 - st) : (st + 1);
      nxa = *(const bf16x8*)(inp + (size_t)f * step_stride);
      nxb = *(const bf16x8*)(inp + (size_t)f * step_stride + 32);
    }
    {
      bf16x8 h0 = *(const bf16x8*)&hfrag[l * 8];
      a0 = mfma16(h0, WB[2], a0);
      if constexpr (NKH == 2) {
        bf16x8 h1 = *(const bf16x8*)&hfrag[(64 + l) * 8];
        a1 = mfma16(h1, WB[3], a1);
      }
    }
    f32x4 acc = a0 + a1;
    {
      uint32_t p01 = cvt_pk_bf16(lecun_tanh_f(acc[0]), lecun_tanh_f(acc[1]));
      uint32_t p23 = cvt_pk_bf16(lecun_tanh_f(acc[2]), lecun_tanh_f(acc[3]));
      gfrag[gi] = (uint16_t)p01;
      gfrag[gi + 8] = (uint16_t)(p01 >> 16);
      gfrag[gi + 16] = (uint16_t)p23;
      gfrag[gi + 24] = (uint16_t)(p23 >> 16);
    }
    block_fence();  // g visible; h reads done before phase-B h overwrite

    // ---- phase B: x-part MFMAs for st+1 (ALL waves) + ff1/state (m-waves) --
    a0 = mfma16(nxa, WB[0], bbv4);
    a1 = mfma16(nxb, WB[1], zero4);
    if (has_m) {
      bf16x8 gf[4];
#pragma unroll
      for (int kt = 0; kt < 4; ++kt)
        gf[kt] = *(const bf16x8*)&gfrag[(kt * 64 + l) * 8];
      f32x4 f0 = mfma16(gf[0], W1f[0], b1v4);
      f32x4 f1 = mfma16(gf[1], W1f[1], zero4);
      f0 = mfma16(gf[2], W1f[2], f0);
      f1 = mfma16(gf[3], W1f[3], f1);
      f32x4 fa = f0 + f1;
      float hn[4];
#pragma unroll
      for (int r = 0; r < 4; ++r) {
        float ff = fa[r];
        float e = asm_exp2(fmaf(-1.4426950408889634f, fabsf(ff), mwt2));
        hn[r] = fmaf(e * ff, nAv, Avv);
      }
      uint32_t p01 = cvt_pk_bf16(hn[0], hn[1]);
      uint32_t p23 = cvt_pk_bf16(hn[2], hn[3]);
      uint16_t hb[4] = {(uint16_t)p01, (uint16_t)(p01 >> 16), (uint16_t)p23,
                        (uint16_t)(p23 >> 16)};
      hfrag[gi] = hb[0];
      hfrag[gi + 8] = hb[1];
      hfrag[gi + 16] = hb[2];
      hfrag[gi + 24] = hb[3];
#pragma unroll
      for (int r = 0; r < 4; ++r)
        if (omask[r]) out[obase[r] + st * o_step_stride] = hb[r];
    }
    block_fence();  // h visible for next step; gfrag WAR protection
  }
}

// ---------- K2/K4: MFMA FC(64x64) + LN(F,H) + residual ----------
template <bool TRANS>
__global__ __launch_bounds__(256) void fc_ln_mfma(
    const uint16_t* __restrict__ yin, const uint16_t* __restrict__ resid,
    const float* __restrict__ W, const float* __restrict__ bias,
    const float* __restrict__ lng, const float* __restrict__ lnb,
    void* __restrict__ outp) {
  __shared__ __align__(16) uint16_t ysh[176 * 72];
  __shared__ float red[16];
  __shared__ float fsh[TRANS ? NF * 73 : 4];

  const int tid = threadIdx.x, n = blockIdx.x;
  const int w = tid >> 6, l = tid & 63, l4 = l >> 4, lm = l & 15;
  const int b = n / 250, t = n - b * 250;

  // stage y -> ysh (rows >=161 zeroed)
  const size_t ybase = TRANS ? ((size_t)b * 40250 + t) * 64 : (size_t)n * GROUP;
  const int rstride = TRANS ? 16000 : 64;
  for (int idx = tid; idx < 176 * 8; idx += 256) {
    int f = idx >> 3, k8 = (idx & 7) * 8;
    uint64_t lo = 0, hi = 0;
    if (f < NF) {
      const uint64_t* p =
          (const uint64_t*)(yin + ybase + (size_t)f * rstride + k8);
      lo = p[0];
      hi = p[1];
    }
    uint64_t* q = (uint64_t*)&ysh[f * 72 + k8];
    q[0] = lo;
    q[1] = hi;
  }

  bf16x8 Wf[2];
#pragma unroll
  for (int kt = 0; kt < 2; ++kt)
    Wf[kt] = pack_frag(&W[(kt * 32 + l4 * 8) * 64 + 16 * w + lm], 64);
  const float bv = bias[16 * w + lm];
  __syncthreads();

  // FC: 11 m-tiles x 2 k-tiles per wave
  f32x4 acc[11];
#pragma unroll
  for (int m = 0; m < 11; ++m) {
    bf16x8 a0 = *(const bf16x8*)&ysh[(m * 16 + lm) * 72 + l4 * 8];
    bf16x8 a1 = *(const bf16x8*)&ysh[(m * 16 + lm) * 72 + 32 + l4 * 8];
    f32x4 c = {bv, bv, bv, bv};
    c = mfma16(a0, Wf[0], c);
    c = mfma16(a1, Wf[1], c);
    acc[m] = c;
  }

  // LN stats (rows >= 161 excluded; m=10 contributes only row 160)
  float sum = 0.f, ssq = 0.f;
#pragma unroll
  for (int m = 0; m < 10; ++m)
#pragma unroll
    for (int r = 0; r < 4; ++r) {
      float v = acc[m][r];
      sum += v;
      ssq += v * v;
    }
  if (l4 == 0) {
    float v = acc[10][0];
    sum += v;
    ssq += v * v;
  }
#pragma unroll
  for (int off = 32; off; off >>= 1) {
    sum += __shfl_xor(sum, off);
    ssq += __shfl_xor(ssq, off);
  }
  if (l == 0) {
    red[w] = sum;
    red[4 + w] = ssq;
  }
  __syncthreads();
  if (tid == 0) {
    float s = red[0] + red[1] + red[2] + red[3];
    float q = red[4] + red[5] + red[6] + red[7];
    float mu = s * (1.f / (float)GROUP);
    float var = q * (1.f / (float)GROUP) - mu * mu;
    red[8] = mu;
    red[9] = rsqrtf(fmaxf(var, 0.f) + 1e-8f);
  }
  __syncthreads();
  const float mu = red[8], rstd = red[9];

  // scatter normalized (pre-affine) back into ysh as bf16
#pragma unroll
  for (int m = 0; m < 11; ++m)
#pragma unroll
    for (int r = 0; r < 4; ++r) {
      int row = m * 16 + l4 * 4 + r;
      if (row < NF)
        ysh[row * 72 + 16 * w + lm] = bf16_rne_u16((acc[m][r] - mu) * rstd);
    }
  __syncthreads();

  // vectorized (x2) affine + residual
  const uint16_t* rrow = resid + (size_t)n * GROUP;
  if (!TRANS) {
    uint16_t* orow = (uint16_t*)outp + (size_t)n * GROUP;
    for (int i2 = tid; i2 < GROUP / 2; i2 += 256) {
      int e0 = 2 * i2;
      int f = e0 >> 6, h = e0 & 63;
      float2 lg = *(const float2*)&lng[e0];
      float2 lb = *(const float2*)&lnb[e0];
      uint32_t rr = *(const uint32_t*)&rrow[e0];
      uint32_t yv = *(const uint32_t*)&ysh[f * 72 + h];
      float v0 = bf16u_to_f((uint16_t)yv) * lg.x + lb.x +
                 bf16u_to_f((uint16_t)rr);
      float v1 = bf16u_to_f((uint16_t)(yv >> 16)) * lg.y + lb.y +
                 bf16u_to_f((uint16_t)(rr >> 16));
      *(uint32_t*)&orow[e0] = cvt_pk_bf16(v0, v1);
    }
  } else {
    for (int i2 = tid; i2 < GROUP / 2; i2 += 256) {
      int e0 = 2 * i2;
      int f = e0 >> 6, h = e0 & 63;
      float2 lg = *(const float2*)&lng[e0];
      float2 lb = *(const float2*)&lnb[e0];
      uint32_t rr = *(const uint32_t*)&rrow[e0];
      uint32_t yv = *(const uint32_t*)&ysh[f * 72 + h];
      fsh[f * 73 + h] = bf16u_to_f((uint16_t)yv) * lg.x + lb.x +
                        bf16u_to_f((uint16_t)rr);
      fsh[f * 73 + h + 1] = bf16u_to_f((uint16_t)(yv >> 16)) * lg.y + lb.y +
                            bf16u_to_f((uint16_t)(rr >> 16));
    }
    __syncthreads();
    float* ob2 = (float*)outp + (size_t)b * 2576000 + (size_t)t * 161;
    for (int idx = tid; idx < GROUP; idx += 256) {
      unsigned h = (unsigned)idx / 161u, f = (unsigned)idx - h * 161u;
      ob2[(size_t)h * 40250 + f] = fsh[f * 73 + h];
    }
  }
}

// ---------- launcher ----------
extern "C" void kernel_launch(void* const* d_in, const int* in_sizes, int n_in,
                              void* d_out, int out_size, void* d_ws,
                              size_t ws_size, hipStream_t stream) {
  const float* x     = (const float*)d_in[0];
  const float* i1_Wb = (const float*)d_in[1];
  const float* i1_bb = (const float*)d_in[2];
  const float* i1_W1 = (const float*)d_in[3];
  const float* i1_b1 = (const float*)d_in[4];
  const float* i1_wt = (const float*)d_in[5];
  const float* i1_A  = (const float*)d_in[6];
  const float* i2_Wb = (const float*)d_in[7];
  const float* i2_bb = (const float*)d_in[8];
  const float* i2_W1 = (const float*)d_in[9];
  const float* i2_b1 = (const float*)d_in[10];
  const float* i2_wt = (const float*)d_in[11];
  const float* i2_A  = (const float*)d_in[12];
  const float* r_Wb  = (const float*)d_in[13];
  const float* r_bb  = (const float*)d_in[14];
  const float* r_W1  = (const float*)d_in[15];
  const float* r_b1  = (const float*)d_in[16];
  const float* r_wt  = (const float*)d_in[17];
  const float* r_A   = (const float*)d_in[18];
  const float* fcW_i = (const float*)d_in[19];
  const float* fcb_i = (const float*)d_in[20];
  const float* lng_i = (const float*)d_in[21];
  const float* lnb_i = (const float*)d_in[22];
  const float* fcW_r = (const float*)d_in[23];
  const float* fcb_r = (const float*)d_in[24];
  const float* lng_r = (const float*)d_in[25];
  const float* lnb_r = (const float*)d_in[26];

  // ws layout: 3 x 41,216,000 B = 123.6 MB
  uint8_t* ws = (uint8_t*)d_ws;
  uint16_t* xp_h    = (uint16_t*)ws;                   // dead after K2
  uint16_t* intra_h = (uint16_t*)(ws + 41216000);      // lives to K4
  uint16_t* inter_h = (uint16_t*)(ws + 82432000);      // K3 out, K4 in
  uint16_t* ybuf    = (uint16_t*)d_out;                // dead after K2

  // K0: x -> xp_h (bf16)
  transpose_kernel<<<dim3(NBT, 6, 2), 256, 0, stream>>>(x, xp_h);

  // K1: intra bidirectional scan over F. 2000 seqs/dir, 16/block -> 125/dir.
  mfma_scan8<32><<<250, 512, 0, stream>>>(
      xp_h, ybuf, i1_Wb, i1_bb, i1_W1, i1_b1, i1_wt, i1_A, i2_Wb, i2_bb, i2_W1,
      i2_b1, i2_wt, i2_A, 161, 125, 2000, 2000, 0, GROUP, 64, GROUP, 64, 32);

  // K2: intra FC + LN + residual(xp_h) -> intra_h (bf16)
  fc_ln_mfma<false><<<NBT, 256, 0, stream>>>(ybuf, xp_h, fcW_i, fcb_i, lng_i,
                                             lnb_i, intra_h);

  // K3: inter scan over T. 1288 seqs -> 81 blocks (tail masked).
  mfma_scan8<64><<<81, 512, 0, stream>>>(
      intra_h, inter_h, r_Wb, r_bb, r_W1, r_b1, r_wt, r_A, r_Wb, r_bb, r_W1,
      r_b1, r_wt, r_A, 250, 81, 1288, 161, 250 * GROUP, 64, GROUP, 16000, 64,
      0);

  // K4: inter FC + LN + residual(intra_h) + transpose -> d_out (B,H,T,F) f32
  fc_ln_mfma<true><<<NBT, 256, 0, stream>>>(inter_h, intra_h, fcW_r, fcb_r,
                                            lng_r, lnb_r, d_out);
}